// Round 1
// baseline (615.761 us; speedup 1.0000x reference)
//
#include <hip/hip_runtime.h>

#define D_FEAT 64

// Initialize output to -inf bit pattern (0xFF800000), vectorized 16B/thread.
__global__ void init_out_kernel(uint4* __restrict__ out, int n4) {
    int i = blockIdx.x * blockDim.x + threadIdx.x;
    if (i < n4) {
        uint4 v;
        v.x = 0xFF800000u; v.y = 0xFF800000u; v.z = 0xFF800000u; v.w = 0xFF800000u;
        out[i] = v;
    }
}

// One wave (64 lanes) per edge; lane = feature index.
// Lane loads h[src*64+lane] (coalesced 256B row), atomically maxes into
// out[dst*64+lane]. Float max via int-max/uint-min trick:
//   v >= 0: int compare matches float compare  -> atomicMax on int
//   v <  0: uint compare is reverse of float   -> atomicMin on uint
// Init sentinel -inf (0xFF800000) is the identity under both paths.
__global__ void scatter_max_kernel(const float* __restrict__ h,
                                   const int* __restrict__ src,
                                   const int* __restrict__ dst,
                                   float* __restrict__ out,
                                   int n_edges) {
    int gid = blockIdx.x * blockDim.x + threadIdx.x;
    int e = gid >> 6;
    if (e >= n_edges) return;
    int lane = gid & 63;

    int s = src[e];   // wave-uniform broadcast load
    int d = dst[e];

    float v = h[s * D_FEAT + lane];
    int* addr = (int*)(out + d * D_FEAT + lane);
    if (v >= 0.0f) {
        atomicMax(addr, __float_as_int(v));
    } else {
        atomicMin((unsigned int*)addr, __float_as_uint(v));
    }
}

// Replace untouched -inf sentinels with 0 (nodes with no incoming edges).
__global__ void finalize_kernel(float* __restrict__ out, int n) {
    int i = blockIdx.x * blockDim.x + threadIdx.x;
    if (i < n) {
        unsigned u = __float_as_uint(out[i]);
        if (u == 0xFF800000u) out[i] = 0.0f;
    }
}

extern "C" void kernel_launch(void* const* d_in, const int* in_sizes, int n_in,
                              void* d_out, int out_size, void* d_ws, size_t ws_size,
                              hipStream_t stream) {
    const float* h = (const float*)d_in[0];
    const int* edge_index = (const int*)d_in[1];
    int n_edges = in_sizes[1] / 2;           // edge_index is [2, E] row-major
    const int* src = edge_index;             // row 0
    const int* dst = edge_index + n_edges;   // row 1
    float* out = (float*)d_out;

    // 1) init out to -inf bits
    int n4 = out_size / 4;
    init_out_kernel<<<(n4 + 255) / 256, 256, 0, stream>>>((uint4*)out, n4);

    // 2) edge scatter-max: one wave per edge, 4 waves per 256-thread block
    long long total_threads = (long long)n_edges * 64;
    int blocks = (int)((total_threads + 255) / 256);
    scatter_max_kernel<<<blocks, 256, 0, stream>>>(h, src, dst, out, n_edges);

    // 3) sentinel -> 0
    finalize_kernel<<<(out_size + 255) / 256, 256, 0, stream>>>(out, out_size);
}

// Round 2
// 330.561 us; speedup vs baseline: 1.8628x; 1.8628x over previous
//
#include <hip/hip_runtime.h>

#define D_FEAT 64
#define NEG_INF_BITS 0xFF800000u
#define SCAN_BLOCK 256
#define SUMS_BLOCK 512

// ======================= CSR path =======================

__global__ void zero_kernel(int* __restrict__ p, int n) {
    int i = blockIdx.x * blockDim.x + threadIdx.x;
    if (i < n) p[i] = 0;
}

__global__ void count_kernel(const int* __restrict__ dst, int* __restrict__ counts, int E) {
    int i = blockIdx.x * blockDim.x + threadIdx.x;
    if (i < E) atomicAdd(&counts[dst[i]], 1);
}

// In-place exclusive scan of data[0..n) per 256-block; block total -> block_sums[b].
__global__ void scan_blocks_kernel(int* __restrict__ data, int* __restrict__ block_sums, int n) {
    __shared__ int lds[SCAN_BLOCK];
    int tid = threadIdx.x;
    int i = blockIdx.x * SCAN_BLOCK + tid;
    int v = (i < n) ? data[i] : 0;
    lds[tid] = v;
    __syncthreads();
    for (int off = 1; off < SCAN_BLOCK; off <<= 1) {
        int t = (tid >= off) ? lds[tid - off] : 0;
        __syncthreads();
        lds[tid] += t;
        __syncthreads();
    }
    int incl = lds[tid];
    if (i < n) data[i] = incl - v;                    // exclusive
    if (tid == SCAN_BLOCK - 1) block_sums[blockIdx.x] = incl;
}

// Single-block exclusive scan of block_sums[0..nb), nb <= 512.
__global__ void scan_sums_kernel(int* __restrict__ block_sums, int nb) {
    __shared__ int lds[SUMS_BLOCK];
    int tid = threadIdx.x;
    int v = (tid < nb) ? block_sums[tid] : 0;
    lds[tid] = v;
    __syncthreads();
    for (int off = 1; off < SUMS_BLOCK; off <<= 1) {
        int t = (tid >= off) ? lds[tid - off] : 0;
        __syncthreads();
        lds[tid] += t;
        __syncthreads();
    }
    if (tid < nb) block_sums[tid] = lds[tid] - v;     // exclusive
}

__global__ void add_offsets_kernel(int* __restrict__ data, const int* __restrict__ block_sums, int n) {
    int i = blockIdx.x * SCAN_BLOCK + threadIdx.x;
    if (i < n) data[i] += block_sums[blockIdx.x];
}

// Advances offsets[d] while filling; post-fill offsets[i] == excl_scan[i+1].
__global__ void fill_kernel(const int* __restrict__ src, const int* __restrict__ dst,
                            int* __restrict__ offsets, int* __restrict__ edge_src, int E) {
    int e = blockIdx.x * blockDim.x + threadIdx.x;
    if (e < E) {
        int pos = atomicAdd(&offsets[dst[e]], 1);
        edge_src[pos] = src[e];
    }
}

// One wave per node, lane = feature. start = offsets[n-1] (post-fill), end = offsets[n].
__global__ void gather_max_kernel(const float* __restrict__ h,
                                  const int* __restrict__ offsets,
                                  const int* __restrict__ edge_src,
                                  float* __restrict__ out, int n_nodes) {
    int gid = blockIdx.x * blockDim.x + threadIdx.x;
    int n = gid >> 6;
    if (n >= n_nodes) return;
    int lane = gid & 63;

    int end = offsets[n];
    int start = (n == 0) ? 0 : offsets[n - 1];

    float m = __uint_as_float(NEG_INF_BITS);
    int e = start;
    for (; e + 4 <= end; e += 4) {
        int s0 = edge_src[e];
        int s1 = edge_src[e + 1];
        int s2 = edge_src[e + 2];
        int s3 = edge_src[e + 3];
        float v0 = h[s0 * D_FEAT + lane];
        float v1 = h[s1 * D_FEAT + lane];
        float v2 = h[s2 * D_FEAT + lane];
        float v3 = h[s3 * D_FEAT + lane];
        m = fmaxf(m, fmaxf(fmaxf(v0, v1), fmaxf(v2, v3)));
    }
    for (; e < end; ++e) {
        m = fmaxf(m, h[edge_src[e] * D_FEAT + lane]);
    }
    out[n * D_FEAT + lane] = (start == end) ? 0.0f : m;
}

// ======================= fallback atomic path =======================

__global__ void init_out_kernel(uint4* __restrict__ out, int n4) {
    int i = blockIdx.x * blockDim.x + threadIdx.x;
    if (i < n4) {
        uint4 v;
        v.x = NEG_INF_BITS; v.y = NEG_INF_BITS; v.z = NEG_INF_BITS; v.w = NEG_INF_BITS;
        out[i] = v;
    }
}

__global__ void scatter_max_kernel(const float* __restrict__ h,
                                   const int* __restrict__ src,
                                   const int* __restrict__ dst,
                                   float* __restrict__ out, int n_edges) {
    int gid = blockIdx.x * blockDim.x + threadIdx.x;
    int e = gid >> 6;
    if (e >= n_edges) return;
    int lane = gid & 63;
    float v = h[src[e] * D_FEAT + lane];
    int* addr = (int*)(out + dst[e] * D_FEAT + lane);
    if (v >= 0.0f) atomicMax(addr, __float_as_int(v));
    else           atomicMin((unsigned int*)addr, __float_as_uint(v));
}

__global__ void finalize_kernel(float* __restrict__ out, int n) {
    int i = blockIdx.x * blockDim.x + threadIdx.x;
    if (i < n) {
        if (__float_as_uint(out[i]) == NEG_INF_BITS) out[i] = 0.0f;
    }
}

// ======================= launch =======================

extern "C" void kernel_launch(void* const* d_in, const int* in_sizes, int n_in,
                              void* d_out, int out_size, void* d_ws, size_t ws_size,
                              hipStream_t stream) {
    const float* h = (const float*)d_in[0];
    const int* edge_index = (const int*)d_in[1];
    int E = in_sizes[1] / 2;                 // edge_index is [2, E] row-major
    const int* src = edge_index;
    const int* dst = edge_index + E;
    float* out = (float*)d_out;
    int N = out_size / D_FEAT;

    int nb = (N + SCAN_BLOCK - 1) / SCAN_BLOCK;       // scan blocks
    size_t ws_needed = (size_t)(N + SUMS_BLOCK + E) * sizeof(int);

    if (ws_size >= ws_needed && nb <= SUMS_BLOCK) {
        int* offsets    = (int*)d_ws;                  // [N]
        int* block_sums = offsets + N;                 // [<=512]
        int* edge_src   = block_sums + SUMS_BLOCK;     // [E]

        zero_kernel<<<(N + 255) / 256, 256, 0, stream>>>(offsets, N);
        count_kernel<<<(E + 255) / 256, 256, 0, stream>>>(dst, offsets, E);
        scan_blocks_kernel<<<nb, SCAN_BLOCK, 0, stream>>>(offsets, block_sums, N);
        scan_sums_kernel<<<1, SUMS_BLOCK, 0, stream>>>(block_sums, nb);
        add_offsets_kernel<<<nb, SCAN_BLOCK, 0, stream>>>(offsets, block_sums, N);
        fill_kernel<<<(E + 255) / 256, 256, 0, stream>>>(src, dst, offsets, edge_src, E);

        long long total = (long long)N * 64;
        gather_max_kernel<<<(int)((total + 255) / 256), 256, 0, stream>>>(h, offsets, edge_src, out, N);
    } else {
        // fallback: atomic scatter path
        int n4 = out_size / 4;
        init_out_kernel<<<(n4 + 255) / 256, 256, 0, stream>>>((uint4*)out, n4);
        long long total = (long long)E * 64;
        scatter_max_kernel<<<(int)((total + 255) / 256), 256, 0, stream>>>(h, src, dst, out, E);
        finalize_kernel<<<(out_size + 255) / 256, 256, 0, stream>>>(out, out_size);
    }
}